// Round 6
// baseline (429.684 us; speedup 1.0000x reference)
//
#include <hip/hip_runtime.h>
#include <hip/hip_bf16.h>
#include <math.h>

#define N_ITEMS 100001
#define DIM 128
#define NP 3
#define SEQ 100
#define NB 256
#define G3 384           // 3*DIM
#define TAU 0.1f
#define EPS_C 0.01f

// ---------------- ws layout (float offsets) ----------------
#define OFF_G     0
#define OFF_C     300016
#define OFF_WXT   600032
#define OFF_WHT   747488
#define OFF_HLAST 894944
#define OFF_GX    993248
// useGx path: wxA_hi/lo (bf16 A-frags of Wx) fill OFF_WXT (2 x 147456 shorts);
// whF_hi/whF_lo (f16 A-frags of Wh, lo scaled x1024) fill OFF_WHT
// (2 x 147456 halves). hl_hi/hl_lo alias the gx region (dead after k_rnn4).
#define WS_FLOATS_PATHA (993248 + 29491200)

typedef float f32x4 __attribute__((ext_vector_type(4)));
typedef short s16x8 __attribute__((ext_vector_type(8)));
typedef _Float16 f16x8 __attribute__((ext_vector_type(8)));

__device__ __forceinline__ float sigmoidf_fast(float x) {
    return __builtin_amdgcn_rcpf(1.f + __builtin_amdgcn_exp2f(-1.4426950408889634f * x));
}
__device__ __forceinline__ float tanhf_fast(float x) {
    return 1.f - 2.f * __builtin_amdgcn_rcpf(1.f + __builtin_amdgcn_exp2f(2.8853900817779268f * x));
}
__device__ __forceinline__ unsigned short f2bf(float x) {
    union { float f; unsigned u; } v; v.f = x;
    unsigned r = v.u + 0x7fffu + ((v.u >> 16) & 1u);
    return (unsigned short)(r >> 16);
}
__device__ __forceinline__ float bf2f(unsigned short h) {
    union { unsigned u; float f; } v; v.u = ((unsigned)h) << 16;
    return v.f;
}

// ---------------- K1 (fallback only): transpose weights to [p][k][j] ----------------
__global__ void k_prep_w(const float* __restrict__ x2h, const float* __restrict__ h2h,
                         float* __restrict__ wxT, float* __restrict__ whT) {
    int idx = blockIdx.x * 256 + threadIdx.x;
    if (idx >= NP * DIM * G3) return;
    int j = idx % G3;
    int k = (idx / G3) % DIM;
    int p = idx / (G3 * DIM);
    wxT[idx] = x2h[((size_t)p * G3 + j) * DIM + k];
    whT[idx] = h2h[((size_t)p * G3 + j) * DIM + k];
}

// ---------------- K1b: Wx -> bf16 hi/lo A-frags; Wh -> f16 hi / scaled-lo A-frags ----------------
// frag f = ((p*24 + mt)*4 + ks)*64 + lane ; holds W[p][mt*16 + (lane&15)]
// [ks*32 + (lane>>4)*8 + 0..7]
__global__ __launch_bounds__(256) void k_prep_wA(const float* __restrict__ x2h,
                                                 const float* __restrict__ h2h,
                                                 short* __restrict__ wxA_hi,
                                                 short* __restrict__ wxA_lo,
                                                 _Float16* __restrict__ whF_hi,
                                                 _Float16* __restrict__ whF_lo) {
    int e = blockIdx.x * 256 + threadIdx.x;       // 2*18432 = 36864
    if (e >= 2 * NP * 24 * 4 * 64) return;
    int which = (e >= NP * 24 * 4 * 64);
    int f = which ? e - NP * 24 * 4 * 64 : e;
    int lane = f & 63;
    int ks = (f >> 6) & 3;
    int mt = (f >> 8) % 24;
    int p  = f / 6144;
    int j = mt * 16 + (lane & 15);
    int d = ks * 32 + (lane >> 4) * 8;
    const float* src = (which ? h2h : x2h) + ((size_t)p * G3 + j) * DIM + d;
    if (which) {
        _Float16 hi[8], lo[8];
#pragma unroll
        for (int u = 0; u < 8; ++u) {
            float x = src[u];
            _Float16 h = (_Float16)x;
            hi[u] = h;
            lo[u] = (_Float16)((x - (float)h) * 1024.f);
        }
        *(f16x8*)(whF_hi + (size_t)f * 8) = *(const f16x8*)hi;
        *(f16x8*)(whF_lo + (size_t)f * 8) = *(const f16x8*)lo;
    } else {
        short hi[8], lo[8];
#pragma unroll
        for (int u = 0; u < 8; ++u) {
            float x = src[u];
            unsigned short h = f2bf(x);
            hi[u] = (short)h;
            lo[u] = (short)f2bf(x - bf2f(h));
        }
        *(s16x8*)(wxA_hi + (size_t)f * 8) = *(const s16x8*)hi;
        *(s16x8*)(wxA_lo + (size_t)f * 8) = *(const s16x8*)lo;
    }
}

// ---------------- K2: per-item norm + softmax(g) + c = g/norm ----------------
__global__ __launch_bounds__(256) void k_gc(const float* __restrict__ emb,
                                            const float* __restrict__ pt,
                                            float* __restrict__ g, float* __restrict__ c) {
    __shared__ float pt_l[G3];
    __shared__ float ainv[NP];
    int tid = threadIdx.x;
    for (int u = tid; u < G3; u += 256) pt_l[u] = pt[u];
    __syncthreads();
    if (tid < NP) {
        float ss = 0.f;
        for (int k = 0; k < DIM; ++k) { float v = pt_l[tid * DIM + k]; ss += v * v; }
        ainv[tid] = 1.f / fmaxf(sqrtf(ss), 1e-12f);
    }
    __syncthreads();
    int lane = tid & 63, wv = tid >> 6;
    for (int it = 0; it < 8; ++it) {
        int i = blockIdx.x * 32 + wv * 8 + it;
        if (i >= N_ITEMS) continue;
        float a = emb[(size_t)i * DIM + lane];
        float b = emb[(size_t)i * DIM + 64 + lane];
        float ss = a * a + b * b;
        float d0 = a * pt_l[lane]       + b * pt_l[64 + lane];
        float d1 = a * pt_l[128 + lane] + b * pt_l[192 + lane];
        float d2 = a * pt_l[256 + lane] + b * pt_l[320 + lane];
        for (int off = 32; off > 0; off >>= 1) {
            ss += __shfl_down(ss, off);
            d0 += __shfl_down(d0, off);
            d1 += __shfl_down(d1, off);
            d2 += __shfl_down(d2, off);
        }
        if (lane == 0) {
            if (i == 0) {
                g[0] = 0.f; g[1] = 0.f; g[2] = 0.f;
                c[0] = 0.f; c[1] = 0.f; c[2] = 0.f;
            } else {
                float inv = 1.f / fmaxf(sqrtf(ss), 1e-12f);
                float l0 = d0 * ainv[0] * inv * (1.f / TAU);
                float l1 = d1 * ainv[1] * inv * (1.f / TAU);
                float l2 = d2 * ainv[2] * inv * (1.f / TAU);
                float m = fmaxf(l0, fmaxf(l1, l2));
                float e0 = expf(l0 - m), e1 = expf(l1 - m), e2 = expf(l2 - m);
                float is = 1.f / (e0 + e1 + e2);
                float g0 = e0 * is, g1 = e1 * is, g2 = e2 * is;
                g[(size_t)i * 3 + 0] = g0; g[(size_t)i * 3 + 1] = g1; g[(size_t)i * 3 + 2] = g2;
                c[(size_t)i * 3 + 0] = g0 * inv; c[(size_t)i * 3 + 1] = g1 * inv; c[(size_t)i * 3 + 2] = g2 * inv;
            }
        }
    }
}

// ---------------- K3 v2: Gx via MFMA ----------------
__global__ __launch_bounds__(512, 2) void k_gx_mfma(const int* __restrict__ seq,
                                                    const float* __restrict__ emb,
                                                    const short* __restrict__ wxA_hi,
                                                    const short* __restrict__ wxA_lo,
                                                    float* __restrict__ gx) {
    int bid = blockIdx.x;
    int t  = bid >> 4;
    int b0 = (bid & 15) * 16;
    int tid = threadIdx.x;
    int lane = tid & 63;
    int w = tid >> 6;
    int n = lane & 15;
    int q = lane >> 4;

    __shared__ int idx_l[16];
    __shared__ __align__(16) unsigned short xH[2048];   // [ks*512 + lane*8 + j]
    __shared__ __align__(16) unsigned short xL[2048];

    if (tid < 16) idx_l[tid] = seq[t * NB + b0 + tid];
    __syncthreads();

    {
        int tk = tid >> 5, s = tid & 31;
        float4 v = *(const float4*)(emb + (size_t)idx_l[tk] * DIM + s * 4);
        int k = s * 4;
        int ks = k >> 5, km = k & 31;
        int ln = (km >> 3) * 16 + tk;
        int j0 = km & 7;
        int o = ks * 512 + ln * 8 + j0;
        float xv[4] = {v.x, v.y, v.z, v.w};
        unsigned short sh[4], sl[4];
#pragma unroll
        for (int r = 0; r < 4; ++r) {
            sh[r] = f2bf(xv[r]);
            sl[r] = f2bf(xv[r] - bf2f(sh[r]));
        }
        *(uint2*)(xH + o) = make_uint2((unsigned)sh[0] | ((unsigned)sh[1] << 16),
                                       (unsigned)sh[2] | ((unsigned)sh[3] << 16));
        *(uint2*)(xL + o) = make_uint2((unsigned)sl[0] | ((unsigned)sl[1] << 16),
                                       (unsigned)sl[2] | ((unsigned)sl[3] << 16));
    }
    __syncthreads();

    s16x8 bh[4], bl[4];
#pragma unroll
    for (int ks = 0; ks < 4; ++ks) {
        bh[ks] = ((const s16x8*)xH)[ks * 64 + lane];
        bl[ks] = ((const s16x8*)xL)[ks * 64 + lane];
    }

    float* gxt = gx + (size_t)(t * 3) * NB * G3;
#pragma unroll 3
    for (int ji = 0; ji < 9; ++ji) {
        int pid = w + ji * 8;           // 0..71
        int p = pid / 24, mt = pid % 24;
        f32x4 acc = {0.f, 0.f, 0.f, 0.f};
#pragma unroll
        for (int ks = 0; ks < 4; ++ks) {
            size_t ao = ((((size_t)p * 24 + mt) * 4 + ks) * 64 + lane) * 8;
            s16x8 ah = *(const s16x8*)(wxA_hi + ao);
            s16x8 al = *(const s16x8*)(wxA_lo + ao);
            acc = __builtin_amdgcn_mfma_f32_16x16x32_bf16(ah, bl[ks], acc, 0, 0, 0);
            acc = __builtin_amdgcn_mfma_f32_16x16x32_bf16(al, bh[ks], acc, 0, 0, 0);
            acc = __builtin_amdgcn_mfma_f32_16x16x32_bf16(ah, bh[ks], acc, 0, 0, 0);
        }
        float* o = gxt + ((size_t)p * NB + b0 + n) * G3 + mt * 16 + q * 4;
        *(float4*)o = make_float4(acc[0], acc[1], acc[2], acc[3]);
    }
}

// ---------------- K4 v4: MFMA recurrence, f16 h-state + 2-term Wh ----------------
// grid 48 = 3p * 16 b-tiles(16). block 512 = 8 waves; wave w owns m-tiles
// {w, w+8, w+16} -> gate triple (r,i,n) for d in [w*16,w*16+16) is in-lane.
// h LDS copy: single f16 B-fragments, double buffered. Wh in regs: f16 hi +
// f16 lo*1024 (2 accumulators, combined as aH + aC/1024).
__global__ __launch_bounds__(512, 2) void k_rnn4(const int* __restrict__ seq,
                                                 const int* __restrict__ lens,
                                                 const float* __restrict__ g,
                                                 const _Float16* __restrict__ whF_hi,
                                                 const _Float16* __restrict__ whF_lo,
                                                 const float* __restrict__ gx,
                                                 float* __restrict__ hlast) {
    int bid = blockIdx.x;
    int p  = bid / 16;
    int b0 = (bid % 16) * 16;
    int tid = threadIdx.x;
    int lane = tid & 63;
    int w = tid >> 6;
    int n = lane & 15;
    int q = lane >> 4;
    int d0 = w * 16 + q * 4;

    __shared__ __align__(16) _Float16 hF[2 * 2048];   // [buf][ks*512 + ln*8 + jj]
    __shared__ float conc_s[SEQ * 16];

    for (int u = tid; u < 4096; u += 512) hF[u] = (_Float16)0.f;

    for (int e = tid; e < SEQ * 16; e += 512) {
        int t = e >> 4, b = e & 15;
        int ix = seq[t * NB + b0 + b];
        float cc = g[(size_t)ix * 3 + p];
        conc_s[e] = (cc >= EPS_C) ? cc : 0.f;
    }

    // Wh A-fragments into registers (f16 hi + scaled lo)
    f16x8 whH[3][4], whLs[3][4];
    int mts0 = w, mts1 = 8 + w, mts2 = 16 + w;
#pragma unroll
    for (int ks = 0; ks < 4; ++ks) {
        size_t o0 = ((((size_t)p * 24 + mts0) * 4 + ks) * 64 + lane) * 8;
        size_t o1 = ((((size_t)p * 24 + mts1) * 4 + ks) * 64 + lane) * 8;
        size_t o2 = ((((size_t)p * 24 + mts2) * 4 + ks) * 64 + lane) * 8;
        whH[0][ks] = *(const f16x8*)(whF_hi + o0);
        whH[1][ks] = *(const f16x8*)(whF_hi + o1);
        whH[2][ks] = *(const f16x8*)(whF_hi + o2);
        whLs[0][ks] = *(const f16x8*)(whF_lo + o0);
        whLs[1][ks] = *(const f16x8*)(whF_lo + o1);
        whLs[2][ks] = *(const f16x8*)(whF_lo + o2);
    }

    int len_n = lens[b0 + n];
    float h0 = 0.f, h1 = 0.f, h2 = 0.f, h3 = 0.f;

    // writer address (in halves): d0..d0+3 -> wks*512 + rl*8 + jj0 (+0..3)
    int wks = d0 >> 5;
    int km  = d0 & 31;
    int rl  = (km >> 3) * 16 + n;
    int jj0 = km & 7;
    int widx = wks * 512 + rl * 8 + jj0;

    const float* gxbase = gx + ((size_t)p * NB + (b0 + n)) * G3 + d0;
    const size_t tstride = (size_t)3 * NB * G3;

    // prefetch distance 2
    f32x4 aR = *(const f32x4*)(gxbase);
    f32x4 aI = *(const f32x4*)(gxbase + DIM);
    f32x4 aN = *(const f32x4*)(gxbase + 2 * DIM);
    f32x4 bR = *(const f32x4*)(gxbase + tstride);
    f32x4 bI = *(const f32x4*)(gxbase + tstride + DIM);
    f32x4 bN = *(const f32x4*)(gxbase + tstride + 2 * DIM);

    __syncthreads();

    int cur = 0;
    for (int t = 0; t < SEQ; ++t) {
        f32x4 grv = aR, giv = aI, gnv = aN;
        aR = bR; aI = bI; aN = bN;
        int tn = (t + 2 < SEQ) ? (t + 2) : (SEQ - 1);
        const float* gp = gxbase + (size_t)tn * tstride;
        bR = *(const f32x4*)(gp);
        bI = *(const f32x4*)(gp + DIM);
        bN = *(const f32x4*)(gp + 2 * DIM);

        float cc = conc_s[t * 16 + n];

        f32x4 aH0 = {0.f,0.f,0.f,0.f}, aH1 = {0.f,0.f,0.f,0.f}, aH2 = {0.f,0.f,0.f,0.f};
        f32x4 aC0 = {0.f,0.f,0.f,0.f}, aC1 = {0.f,0.f,0.f,0.f}, aC2 = {0.f,0.f,0.f,0.f};
        const f16x8* bp = (const f16x8*)hF + cur * 256 + lane;
#pragma unroll
        for (int ks = 0; ks < 4; ++ks) {
            f16x8 bh = bp[ks * 64];
            aH0 = __builtin_amdgcn_mfma_f32_16x16x32_f16(whH[0][ks], bh, aH0, 0, 0, 0);
            aH1 = __builtin_amdgcn_mfma_f32_16x16x32_f16(whH[1][ks], bh, aH1, 0, 0, 0);
            aH2 = __builtin_amdgcn_mfma_f32_16x16x32_f16(whH[2][ks], bh, aH2, 0, 0, 0);
            aC0 = __builtin_amdgcn_mfma_f32_16x16x32_f16(whLs[0][ks], bh, aC0, 0, 0, 0);
            aC1 = __builtin_amdgcn_mfma_f32_16x16x32_f16(whLs[1][ks], bh, aC1, 0, 0, 0);
            aC2 = __builtin_amdgcn_mfma_f32_16x16x32_f16(whLs[2][ks], bh, aC2, 0, 0, 0);
        }

        float gr4[4], gi4[4], gn4[4];
        *(f32x4*)gr4 = grv; *(f32x4*)gi4 = giv; *(f32x4*)gn4 = gnv;
        float hh[4] = {h0, h1, h2, h3};
        float hnew[4];
#pragma unroll
        for (int r = 0; r < 4; ++r) {
            float ar = aH0[r] + aC0[r] * (1.f / 1024.f);
            float ai = aH1[r] + aC1[r] * (1.f / 1024.f);
            float an = aH2[r] + aC2[r] * (1.f / 1024.f);
            float rr = sigmoidf_fast(gr4[r] + ar);
            float ig = sigmoidf_fast(gi4[r] + ai);
            float ng = tanhf_fast(gn4[r] + rr * an);
            float m2 = cc * ig;
            hnew[r] = hh[r] + m2 * (ng - hh[r]);
        }
        h0 = hnew[0]; h1 = hnew[1]; h2 = hnew[2]; h3 = hnew[3];

        if (t == len_n - 1) {
            float* hp = hlast + (size_t)(b0 + n) * G3 + p * DIM + d0;
            *(float4*)hp = make_float4(h0, h1, h2, h3);
        }

        union { _Float16 hf[4]; uint2 u2; } pk;
#pragma unroll
        for (int r = 0; r < 4; ++r) pk.hf[r] = (_Float16)hnew[r];
        *(uint2*)(hF + (cur ^ 1) * 2048 + widx) = pk.u2;
        __syncthreads();
        cur ^= 1;
    }
}

// ---------------- K4 fallback (no gx buffer) ----------------
__global__ __launch_bounds__(384) void k_rnn(const int* __restrict__ seq,
                                             const int* __restrict__ lens,
                                             const float* __restrict__ emb,
                                             const float* __restrict__ g,
                                             const float* __restrict__ wxT,
                                             const float* __restrict__ whT,
                                             float* __restrict__ hlast) {
    int bid = blockIdx.x;
    int b0 = (bid & 63) * 4;
    int p = bid >> 6;
    __shared__ __align__(16) float h_l[DIM * 4];
    __shared__ __align__(16) float x_l[DIM * 4];
    __shared__ __align__(16) float sx_l[G3 * 4];
    __shared__ __align__(16) float sh_l[G3 * 4];
    __shared__ float conc_l[4];
    __shared__ int idx_l[4];
    __shared__ int len_l[4];
    int tid = threadIdx.x;
    if (tid < 4) len_l[tid] = lens[b0 + tid];
    for (int u = tid; u < DIM * 4; u += 384) h_l[u] = 0.f;
    __syncthreads();
    const float* wh = whT + (size_t)p * (DIM * G3);
    const float* wx = wxT + (size_t)p * (DIM * G3);
    for (int t = 0; t < SEQ; ++t) {
        if (tid < 4) {
            int ix = seq[t * NB + b0 + tid];
            idx_l[tid] = ix;
            conc_l[tid] = g[(size_t)ix * 3 + p];
        }
        __syncthreads();
        for (int u = tid; u < DIM * 4; u += 384) {
            int bc = u >> 7, k = u & 127;
            x_l[k * 4 + bc] = emb[(size_t)idx_l[bc] * DIM + k];
        }
        __syncthreads();
        int j = tid;
        float ax0 = 0.f, ax1 = 0.f, ax2 = 0.f, ax3 = 0.f;
#pragma unroll 4
        for (int k = 0; k < DIM; ++k) {
            float wv = wx[(size_t)k * G3 + j];
            float4 xv = *(const float4*)(x_l + k * 4);
            ax0 += wv * xv.x; ax1 += wv * xv.y; ax2 += wv * xv.z; ax3 += wv * xv.w;
        }
        float ah0 = 0.f, ah1 = 0.f, ah2 = 0.f, ah3 = 0.f;
#pragma unroll 4
        for (int k = 0; k < DIM; ++k) {
            float wv = wh[(size_t)k * G3 + j];
            float4 hv = *(const float4*)(h_l + k * 4);
            ah0 += wv * hv.x; ah1 += wv * hv.y; ah2 += wv * hv.z; ah3 += wv * hv.w;
        }
        *(float4*)(sx_l + j * 4) = make_float4(ax0, ax1, ax2, ax3);
        *(float4*)(sh_l + j * 4) = make_float4(ah0, ah1, ah2, ah3);
        __syncthreads();
        for (int u = tid; u < DIM * 4; u += 384) {
            int bc = u & 3, d = u >> 2;
            float sr = sx_l[d * 4 + bc] + sh_l[d * 4 + bc];
            float si = sx_l[(DIM + d) * 4 + bc] + sh_l[(DIM + d) * 4 + bc];
            float xn = sx_l[(2 * DIM + d) * 4 + bc];
            float hn = sh_l[(2 * DIM + d) * 4 + bc];
            float r  = sigmoidf_fast(sr);
            float ig = sigmoidf_fast(si);
            float ng = tanhf_fast(xn + r * hn);
            float h  = h_l[d * 4 + bc];
            float cc = conc_l[bc];
            float multi = (cc >= EPS_C ? cc : 0.f) * ig;
            float hnew = h + multi * (ng - h);
            h_l[d * 4 + bc] = hnew;
            if (t == len_l[bc] - 1)
                hlast[(size_t)(b0 + bc) * G3 + p * DIM + d] = hnew;
        }
        __syncthreads();
    }
}

// ---------------- K4.5: split hlast into bf16 hi/lo, packed in A-fragment order ----------------
__global__ __launch_bounds__(256) void k_prep_h(const float* __restrict__ hlast,
                                                short* __restrict__ hl_hi,
                                                short* __restrict__ hl_lo) {
    int e = blockIdx.x * 256 + threadIdx.x;       // 98304
    int b = e / G3;
    int k = e % G3;
    float x = hlast[e];
    unsigned short hi = f2bf(x);
    unsigned short lo = f2bf(x - bf2f(hi));
    int off = (k >> 5) * 8192 + b * 32 + ((k >> 3) & 3) * 8 + (k & 7);
    hl_hi[off] = (short)hi;
    hl_lo[off] = (short)lo;
}

// ---------------- K5: logits via bf16 MFMA hi/lo (3-term), out = sigmoid ----------------
__global__ __launch_bounds__(256) void k_logits_mfma(const float* __restrict__ emb,
                                                     const float* __restrict__ c,
                                                     const short* __restrict__ hl_hi,
                                                     const short* __restrict__ hl_lo,
                                                     float* __restrict__ out) {
    int i0 = blockIdx.x * 64;
    int tid = threadIdx.x;
    int w = tid >> 6;
    int lane = tid & 63;
    int n = lane & 15;
    int q = lane >> 4;

    __shared__ __align__(16) float embs[64 * 132];

    for (int u = tid; u < 64 * 32; u += 256) {
        int i = u >> 5;
        int s = u & 31;
        int gi = i0 + i;
        float4 v = make_float4(0.f, 0.f, 0.f, 0.f);
        if (gi < N_ITEMS) v = *(const float4*)(emb + (size_t)gi * DIM + s * 4);
        *(float4*)(embs + i * 132 + s * 4) = v;
    }

    float cv[4][3];
#pragma unroll
    for (int is = 0; is < 4; ++is) {
        int gi = i0 + is * 16 + n;
#pragma unroll
        for (int p = 0; p < 3; ++p)
            cv[is][p] = (gi < N_ITEMS) ? c[(size_t)gi * 3 + p] : 0.f;
    }
    __syncthreads();

    f32x4 acc[4][4];
#pragma unroll
    for (int bs = 0; bs < 4; ++bs)
#pragma unroll
        for (int is = 0; is < 4; ++is)
            acc[bs][is] = (f32x4){0.f, 0.f, 0.f, 0.f};

    for (int ks = 0; ks < 12; ++ks) {
        int p = ks >> 2;
        int d0 = (ks & 3) * 32;
        int abase = ks * 8192 + (w * 64 + n) * 32 + q * 8;
        s16x8 ah[4], al[4];
#pragma unroll
        for (int bs = 0; bs < 4; ++bs) {
            ah[bs] = *(const s16x8*)(hl_hi + abase + bs * 512);
            al[bs] = *(const s16x8*)(hl_lo + abase + bs * 512);
        }
#pragma unroll
        for (int is = 0; is < 4; ++is) {
            const float* src = embs + (is * 16 + n) * 132 + d0 + q * 8;
            float x[8];
            *(float4*)(x)     = *(const float4*)(src);
            *(float4*)(x + 4) = *(const float4*)(src + 4);
            float sc = cv[is][p];
            s16x8 bhv, blv;
#pragma unroll
            for (int j = 0; j < 8; ++j) {
                float v = x[j] * sc;
                unsigned short h = f2bf(v);
                bhv[j] = (short)h;
                blv[j] = (short)f2bf(v - bf2f(h));
            }
#pragma unroll
            for (int bs = 0; bs < 4; ++bs) {
                acc[bs][is] = __builtin_amdgcn_mfma_f32_16x16x32_bf16(ah[bs], blv, acc[bs][is], 0, 0, 0);
                acc[bs][is] = __builtin_amdgcn_mfma_f32_16x16x32_bf16(al[bs], bhv, acc[bs][is], 0, 0, 0);
                acc[bs][is] = __builtin_amdgcn_mfma_f32_16x16x32_bf16(ah[bs], bhv, acc[bs][is], 0, 0, 0);
            }
        }
    }

#pragma unroll
    for (int is = 0; is < 4; ++is) {
        int gi = i0 + is * 16 + n;
        if (gi >= N_ITEMS) continue;
#pragma unroll
        for (int bs = 0; bs < 4; ++bs) {
            int brow = w * 64 + bs * 16 + q * 4;
#pragma unroll
            for (int r = 0; r < 4; ++r)
                out[(size_t)(brow + r) * N_ITEMS + gi] = sigmoidf_fast(acc[bs][is][r]);
        }
    }
}

extern "C" void kernel_launch(void* const* d_in, const int* in_sizes, int n_in,
                              void* d_out, int out_size, void* d_ws, size_t ws_size,
                              hipStream_t stream) {
    const int*   seq  = (const int*)d_in[0];
    const int*   lens = (const int*)d_in[1];
    const float* emb  = (const float*)d_in[2];
    const float* pt   = (const float*)d_in[3];
    const float* x2h  = (const float*)d_in[4];
    const float* h2h  = (const float*)d_in[5];
    float* out = (float*)d_out;
    float* ws  = (float*)d_ws;

    float* g     = ws + OFF_G;
    float* c     = ws + OFF_C;
    float* wxT   = ws + OFF_WXT;
    float* whT   = ws + OFF_WHT;
    float* hlast = ws + OFF_HLAST;
    float* gxbuf = ws + OFF_GX;
    short* wxA_hi = (short*)(ws + OFF_WXT);
    short* wxA_lo = wxA_hi + 147456;
    _Float16* whF_hi = (_Float16*)(ws + OFF_WHT);
    _Float16* whF_lo = whF_hi + 147456;
    short* hl_hi = (short*)(ws + OFF_GX);       // aliases gx (dead after k_rnn4)
    short* hl_lo = hl_hi + 98304;

    int useGx = (ws_size >= (size_t)WS_FLOATS_PATHA * 4) ? 1 : 0;

    k_gc<<<3126, 256, 0, stream>>>(emb, pt, g, c);
    if (useGx) {
        k_prep_wA<<<144, 256, 0, stream>>>(x2h, h2h, wxA_hi, wxA_lo, whF_hi, whF_lo);
        k_gx_mfma<<<1600, 512, 0, stream>>>(seq, emb, wxA_hi, wxA_lo, gxbuf);
        k_rnn4<<<48, 512, 0, stream>>>(seq, lens, g, whF_hi, whF_lo, gxbuf, hlast);
    } else {
        k_prep_w<<<576, 256, 0, stream>>>(x2h, h2h, wxT, whT);
        k_rnn<<<192, 384, 0, stream>>>(seq, lens, emb, g, wxT, whT, hlast);
    }
    k_prep_h<<<384, 256, 0, stream>>>(hlast, hl_hi, hl_lo);
    k_logits_mfma<<<1563, 256, 0, stream>>>(emb, c, hl_hi, hl_lo, out);
}